// Round 4
// baseline (831.937 us; speedup 1.0000x reference)
//
#include <hip/hip_runtime.h>

typedef unsigned short u16;
typedef unsigned int   u32;
typedef __bf16 bf16x8 __attribute__((ext_vector_type(8)));
typedef float  f32x4  __attribute__((ext_vector_type(4)));
typedef u32    u32x2  __attribute__((ext_vector_type(2)));

#define NS 256              // samples (M)
#define KF 10000            // features (K)
#define KP 10048            // padded K (multiple of 64)
#define NO 15000            // outputs (N)
#define NP 15104            // padded N = 118*128
#define BM 256
#define BN 128
#define BK 32
#define KHALF (KP/2)        // 5024
#define NSTEPS (KHALF/BK)   // 157
#define COVR 150
#define NA 100

// ---------------- prep: BatchNorm affine + fp32 -> bf16 hi/lo split ----------------
__global__ void k_prep_x(const float* __restrict__ x, const float* __restrict__ gamma,
                         const float* __restrict__ beta, const float* __restrict__ rmean,
                         const float* __restrict__ rvar,
                         u16* __restrict__ xnh, u16* __restrict__ xnl)
{
    int k = blockIdx.x * 256 + threadIdx.x;
    int s = blockIdx.y;
    if (k >= KP) return;
    float v = 0.0f;
    if (k < KF) {
        float xv = x[(size_t)s * KF + k];
        v = (xv - rmean[k]) * (gamma[k] * rsqrtf(rvar[k] + 1e-5f)) + beta[k];
    }
    u32 bits = __float_as_uint(v);
    u32 hb   = bits & 0xffff0000u;
    float lo = v - __uint_as_float(hb);
    xnh[(size_t)s * KP + k] = (u16)(hb >> 16);
    xnl[(size_t)s * KP + k] = (u16)(__float_as_uint(lo) >> 16);
}

__device__ __forceinline__ void split_pack(float v0, float v1, u32& hp, u32& lp)
{
    u32 b0 = __float_as_uint(v0), b1 = __float_as_uint(v1);
    u32 h0 = b0 & 0xffff0000u,   h1 = b1 & 0xffff0000u;
    hp = (h0 >> 16) | h1;
    float r0 = v0 - __uint_as_float(h0);
    float r1 = v1 - __uint_as_float(h1);
    lp = (__float_as_uint(r0) >> 16) | (__float_as_uint(r1) & 0xffff0000u);
}

__device__ __forceinline__ void gload16(const u16* g, u16* l)
{
    __builtin_amdgcn_global_load_lds(
        (const __attribute__((address_space(1))) void*)g,
        (__attribute__((address_space(3))) void*)l, 16, 0, 0);
}

// ---------------- GEMM: Yp[ks] = Xn * W^T (3-term bf16 split), split-K=2 ----------------
// 1024 thr (16 waves, 4M x 4N, wave tile 64x32), BM=256 x BN=128, BK=32, dbuf LDS 96KB.
// 3 phases/step; counted vmcnt(1); A via global_load_lds, W reg-staged one step early.
__global__ __launch_bounds__(1024, 4) void k_gemm(
    const u16* __restrict__ xnh, const u16* __restrict__ xnl,
    const float* __restrict__ W, float* __restrict__ Yp)
{
    __shared__ u16 Ah[2][BM * BK];
    __shared__ u16 Al[2][BM * BK];
    __shared__ u16 Bh[2][BN * BK];
    __shared__ u16 Bl[2][BN * BK];

    const int t    = threadIdx.x;
    const int wv   = t >> 6;
    const int n0   = blockIdx.x * BN;
    const int ks   = blockIdx.y;
    const int kbeg = ks * KHALF;

    // A staging: thread t -> LDS slot t (16B), global chunk pre-swizzled
    const int rA = t >> 2;
    const int uA = t & 3;
    const int cA = uA ^ ((rA >> 1) & 3);
    const size_t eA = (size_t)rA * KP + cA * 8;

    // W staging: thread t -> row rB, swizzled 8-elem chunk ch, half h2 (4 f32)
    const int rB  = t >> 3;
    const int ch  = (t >> 1) & 3;
    const int h2  = t & 1;
    const int gc  = ch ^ ((rB >> 1) & 3);
    const int kin = gc * 8 + h2 * 4;
    const int oW  = n0 + rB;
    const bool oOk = (oW < NO);
    const size_t eW = (size_t)(oOk ? oW : 0) * KF + kin;
    const int boff = rB * 32 + ch * 8 + h2 * 4;   // LDS elem offset (u16)

    // compute-side lane constants
    const int lane = t & 63;
    const int wm   = wv & 3;    // 4 M-groups of 64
    const int wn   = wv >> 2;   // 4 N-groups of 32
    const int l15  = lane & 15;
    const int lc   = lane >> 4;
    const int q    = (l15 >> 1) & 3;
    const int eoff = l15 * BK + ((lc ^ q) << 3);

    f32x4 acc[4][2];
#pragma unroll
    for (int m = 0; m < 4; ++m)
#pragma unroll
        for (int n = 0; n < 2; ++n) { acc[m][n][0]=0.f; acc[m][n][1]=0.f; acc[m][n][2]=0.f; acc[m][n][3]=0.f; }

    auto issueA = [&](int nb, int k1) {
        gload16(xnh + eA + k1, Ah[nb] + (wv << 9));
        gload16(xnl + eA + k1, Al[nb] + (wv << 9));
    };
    auto stageB = [&](int nb, f32x4 wv4, float msk) {
        wv4 *= msk;
        u32 h0, l0, h1, l1;
        split_pack(wv4[0], wv4[1], h0, l0);
        split_pack(wv4[2], wv4[3], h1, l1);
        u32x2 hv; hv[0] = h0; hv[1] = h1;
        u32x2 lv; lv[0] = l0; lv[1] = l1;
        *(u32x2*)(Bh[nb] + boff) = hv;
        *(u32x2*)(Bl[nb] + boff) = lv;
    };

    // prologue: A(0) DMA -> buf0; W(0) -> regs -> LDS buf0
    {
        issueA(0, kbeg);
        asm volatile("" ::: "memory");
        const bool okk = oOk && (kbeg + kin + 4 <= KF);
        const size_t wofs = okk ? (eW + kbeg) : 0;
        f32x4 w0 = *(const f32x4*)(W + wofs);
        stageB(0, w0, okk ? 1.f : 0.f);
    }

#pragma unroll 1
    for (int step = 0; step < NSTEPS; ++step) {
        const int p  = step & 1;
        const int nb = p ^ 1;
        const bool hasNext = (step + 1) < NSTEPS;
        const int k1 = kbeg + (step + 1) * BK;

        f32x4 nw; float nmsk = 0.f;
        if (hasNext) {
            const bool okk = oOk && (k1 + kin + 4 <= KF);
            const size_t wofs = okk ? (eW + k1) : 0;
            nw = *(const f32x4*)(W + wofs);
            nmsk = okk ? 1.f : 0.f;
        }

        if (hasNext) { asm volatile("s_waitcnt vmcnt(1) lgkmcnt(0)" ::: "memory"); }
        else         { asm volatile("s_waitcnt vmcnt(0) lgkmcnt(0)" ::: "memory"); }
        __builtin_amdgcn_s_barrier();
        asm volatile("" ::: "memory");

        if (hasNext) { issueA(nb, k1); asm volatile("" ::: "memory"); }

        const u16* AhL = Ah[p]; const u16* AlL = Al[p];
        const u16* BhL = Bh[p]; const u16* BlL = Bl[p];

        // ---- phase 1: hh ----
        bf16x8 fah[4], fbh[2];
#pragma unroll
        for (int m = 0; m < 4; ++m) fah[m] = *(const bf16x8*)(AhL + (wm * 64 + m * 16) * BK + eoff);
#pragma unroll
        for (int n = 0; n < 2; ++n) fbh[n] = *(const bf16x8*)(BhL + (wn * 32 + n * 16) * BK + eoff);
        __builtin_amdgcn_s_barrier();
        __builtin_amdgcn_s_setprio(1);
#pragma unroll
        for (int m = 0; m < 4; ++m)
#pragma unroll
            for (int n = 0; n < 2; ++n)
                acc[m][n] = __builtin_amdgcn_mfma_f32_16x16x32_bf16(fah[m], fbh[n], acc[m][n], 0, 0, 0);
        __builtin_amdgcn_s_setprio(0);
        __builtin_amdgcn_sched_barrier(0);

        // ---- phase 2: hl ----
        bf16x8 fbl[2];
#pragma unroll
        for (int n = 0; n < 2; ++n) fbl[n] = *(const bf16x8*)(BlL + (wn * 32 + n * 16) * BK + eoff);
        __builtin_amdgcn_s_barrier();
        __builtin_amdgcn_s_setprio(1);
#pragma unroll
        for (int m = 0; m < 4; ++m)
#pragma unroll
            for (int n = 0; n < 2; ++n)
                acc[m][n] = __builtin_amdgcn_mfma_f32_16x16x32_bf16(fah[m], fbl[n], acc[m][n], 0, 0, 0);
        __builtin_amdgcn_s_setprio(0);
        __builtin_amdgcn_sched_barrier(0);

        // ---- phase 3: lh ----
        bf16x8 fal[4];
#pragma unroll
        for (int m = 0; m < 4; ++m) fal[m] = *(const bf16x8*)(AlL + (wm * 64 + m * 16) * BK + eoff);
        __builtin_amdgcn_s_barrier();
        __builtin_amdgcn_s_setprio(1);
#pragma unroll
        for (int m = 0; m < 4; ++m)
#pragma unroll
            for (int n = 0; n < 2; ++n)
                acc[m][n] = __builtin_amdgcn_mfma_f32_16x16x32_bf16(fal[m], fbh[n], acc[m][n], 0, 0, 0);
        __builtin_amdgcn_s_setprio(0);
        __builtin_amdgcn_sched_barrier(0);

        if (hasNext) stageB(nb, nw, nmsk);
    }

    // epilogue: C/D layout col = lane&15, row = (lane>>4)*4 + reg
    const int rowb = wm * 64 + lc * 4;
    const int colb = n0 + wn * 32 + l15;
#pragma unroll
    for (int m = 0; m < 4; ++m)
#pragma unroll
        for (int n = 0; n < 2; ++n) {
            const size_t base = ((size_t)(ks * NS + rowb + m * 16)) * NP + colb + n * 16;
            Yp[base]          = acc[m][n][0];
            Yp[base + NP]     = acc[m][n][1];
            Yp[base + 2*NP]   = acc[m][n][2];
            Yp[base + 3*NP]   = acc[m][n][3];
        }
}

// ---------------- per-sample: fused (reduce+bias+relu) -> cov -> chol -> w ----------------
// 512 thr. One r-pass builds Sum(yy^T) (two teams) AND column sums; A = (S - 150 mu mu^T)/149.
// Cholesky: reg tiles, 1 barrier/col. Triangular solves: single wave, shuffle, 0 barriers.
__global__ __launch_bounds__(512, 1) void k_solve(const float* __restrict__ Yp,
                                                  const float* __restrict__ bias,
                                                  float* __restrict__ out)
{
    __shared__ float Ylds[15008];
    __shared__ float Lsh[13448];        // cov-partial buffer, then L (col-major, stride 105)
    __shared__ float mu[128];
    __shared__ float musum[2][112];
    __shared__ float dgi[112];
    __shared__ float usol[112];
    __shared__ float colbuf[2][112];
    __shared__ float redv[2];

    const int s = blockIdx.x;
    const int t = threadIdx.x;

    // fused split-K reduce + bias + relu into LDS
    const float* y0 = Yp + (size_t)s * NP;
    const float* y1 = Yp + (size_t)(NS + s) * NP;
    for (int o = t; o < 15000; o += 512)
        Ylds[o] = fmaxf(y0[o] + y1[o] + bias[o], 0.f);
    if (t < 8) Ylds[15000 + t] = 0.f;
    if (t >= 100 && t < 128) mu[t] = 0.f;
    if (t >= 104 && t < 112) { colbuf[0][t] = 0.f; colbuf[1][t] = 0.f; }
    __syncthreads();

    // two-team raw second-moment pass + column sums (by the ai==13 threads)
    const int team = t >> 8;
    const int tt   = t & 255;
    const int ai   = tt >> 4;
    const int bj   = tt & 15;
    const int r0   = ai * 8;
    const int c0   = bj * 7;
    const bool act = (ai < 13) && (bj < 15);
    const bool sumduty = (ai == 13);
    const int rbeg = team * 75;

    float A[8][7];
#pragma unroll
    for (int i = 0; i < 8; ++i)
#pragma unroll
        for (int j = 0; j < 7; ++j) A[i][j] = 0.f;
    float cs[7];
#pragma unroll
    for (int j = 0; j < 7; ++j) cs[j] = 0.f;

    for (int r = rbeg; r < rbeg + 75; ++r) {
        if (act) {
            float mi[8], mj[7];
#pragma unroll
            for (int i = 0; i < 8; ++i) mi[i] = Ylds[r * NA + r0 + i];
#pragma unroll
            for (int j = 0; j < 7; ++j) mj[j] = Ylds[r * NA + c0 + j];
#pragma unroll
            for (int i = 0; i < 8; ++i)
#pragma unroll
                for (int j = 0; j < 7; ++j) A[i][j] += mi[i] * mj[j];
        } else if (sumduty) {
#pragma unroll
            for (int j = 0; j < 7; ++j)
                if (c0 + j < NA) cs[j] += Ylds[r * NA + c0 + j];
        }
    }
    if (sumduty) {
#pragma unroll
        for (int j = 0; j < 7; ++j)
            if (c0 + j < NA) musum[team][c0 + j] = cs[j];
    }
    // team 1 publishes its partial tile
    if (team == 1 && act) {
#pragma unroll
        for (int i = 0; i < 8; ++i)
#pragma unroll
            for (int j = 0; j < 7; ++j)
                Lsh[(r0 + i) * 105 + (c0 + j)] = A[i][j];
    }
    __syncthreads();
    if (t < NA) mu[t] = (musum[0][t] + musum[1][t]) * (1.0f / COVR);
    __syncthreads();

    // team 0 merges: A = (S0 + S1 - 150 mu mu^T)/149
    if (team == 0 && act) {
        float mui[8], muj[7];
#pragma unroll
        for (int i = 0; i < 8; ++i) mui[i] = mu[r0 + i];
#pragma unroll
        for (int j = 0; j < 7; ++j) muj[j] = mu[c0 + j];
#pragma unroll
        for (int i = 0; i < 8; ++i)
#pragma unroll
            for (int j = 0; j < 7; ++j)
                A[i][j] = (A[i][j] + Lsh[(r0 + i) * 105 + (c0 + j)]
                           - (float)COVR * mui[i] * muj[j]) * (1.0f / 149.0f);
    }
    // seed column 0
    if (team == 0 && bj == 0 && ai < 13) {
#pragma unroll
        for (int i = 0; i < 8; ++i) colbuf[0][r0 + i] = A[i][0];
    }
    __syncthreads();

    // Cholesky: 1 barrier per column; L stored col-major Lsh[j*105+row]
    for (int j = 0; j < NA; ++j) {
        const int cb = j & 1;
        const float d = sqrtf(colbuf[cb][j]);
        const float dinv = 1.0f / d;
        if (t == 0) dgi[j] = dinv;

        if (team == 0 && act) {
            float Lr[8], Lc[7];
#pragma unroll
            for (int i = 0; i < 8; ++i) {
                const int row = r0 + i;
                const float cv = colbuf[cb][row];
                Lr[i] = (row > j) ? cv * dinv : (row == j ? d : 0.f);
            }
#pragma unroll
            for (int k = 0; k < 7; ++k) {
                const int col = c0 + k;
                const float cv = colbuf[cb][col];
                Lc[k] = (col > j) ? cv * dinv : (col == j ? d : 0.f);
            }
#pragma unroll
            for (int i = 0; i < 8; ++i)
#pragma unroll
                for (int k = 0; k < 7; ++k) A[i][k] -= Lr[i] * Lc[k];

            // owners of column j store L column (incl diag)
            if (bj == j / 7) {
#pragma unroll
                for (int i = 0; i < 8; ++i) Lsh[j * 105 + r0 + i] = Lr[i];
            }
            // owners of column j+1 publish its updated values
            if (j + 1 < NA) {
                const int bjn = (j + 1) / 7;
                if (bj == bjn) {
                    const int jc = (j + 1) - bjn * 7;
#pragma unroll
                    for (int i = 0; i < 8; ++i) colbuf[cb ^ 1][r0 + i] = A[i][jc];
                }
            }
        }
        __syncthreads();
    }

    // triangular solves: wave 0 only, shuffle broadcast, no barriers
    if (t < 64) {
        float r0c = 1.f, r1c = 1.f;
        float y0c = 0.f, y1c = 0.f;
        for (int j = 0; j < NA; ++j) {
            const float dj = dgi[j];
            float src = (j < 64) ? __shfl(r0c, j) : __shfl(r1c, j - 64);
            const float yj = src * dj;
            if (t == j) y0c = yj;
            if (t + 64 == j) y1c = yj;
            const float l0 = Lsh[j * 105 + t];
            const float l1 = Lsh[j * 105 + t + 64];
            if (t > j) r0c -= l0 * yj;
            if (t < 36 && t + 64 > j) r1c -= l1 * yj;
        }
        float u0c = 0.f, u1c = 0.f;
        for (int j = NA - 1; j >= 0; --j) {
            const float dj = dgi[j];
            float src = (j >= 64) ? __shfl(y1c, j - 64) : __shfl(y0c, j);
            const float uj = src * dj;
            if (t == j) u0c = uj;
            if (t + 64 == j) u1c = uj;
            const float l0 = Lsh[t * 105 + j];
            const float l1 = Lsh[(t + 64) * 105 + j];
            if (t < j) y0c -= l0 * uj;
            if (t < 36 && t + 64 < j) y1c -= l1 * uj;
        }
        usol[t] = u0c;
        if (t < 36) usol[t + 64] = u1c;
        float v = u0c + ((t < 36) ? u1c : 0.f);
        for (int off = 32; off > 0; off >>= 1) v += __shfl_xor(v, off);
        if (t == 0) redv[0] = 1.0f / v;
    }
    __syncthreads();
    if (t < NA) out[s * NA + t] = usol[t] * redv[0];
}

// ---------------- launcher ----------------
extern "C" void kernel_launch(void* const* d_in, const int* in_sizes, int n_in,
                              void* d_out, int out_size, void* d_ws, size_t ws_size,
                              hipStream_t stream)
{
    const float* x     = (const float*)d_in[0];
    const float* gamma = (const float*)d_in[1];
    const float* beta  = (const float*)d_in[2];
    const float* rm    = (const float*)d_in[3];
    const float* rv    = (const float*)d_in[4];
    const float* W     = (const float*)d_in[5];
    const float* b     = (const float*)d_in[6];
    float* out = (float*)d_out;

    char* ws = (char*)d_ws;
    u16*   xnh = (u16*)ws;                              // 5,144,576 B
    u16*   xnl = (u16*)(ws + 5144576);                  // 5,144,576 B
    float* Yp  = (float*)(ws + 10289152);               // 30,932,992 B
    (void)in_sizes; (void)n_in; (void)out_size; (void)ws_size;

    k_prep_x<<<dim3(40, NS), 256, 0, stream>>>(x, gamma, beta, rm, rv, xnh, xnl);
    k_gemm  <<<dim3(NP / BN, 2), 1024, 0, stream>>>(xnh, xnl, W, Yp);
    k_solve <<<dim3(NS), 512, 0, stream>>>(Yp, b, out);
}

// Round 5
// 480.091 us; speedup vs baseline: 1.7329x; 1.7329x over previous
//
#include <hip/hip_runtime.h>

typedef unsigned short u16;
typedef unsigned int   u32;
typedef __bf16 bf16x8 __attribute__((ext_vector_type(8)));
typedef float  f32x4  __attribute__((ext_vector_type(4)));
typedef u32    u32x2  __attribute__((ext_vector_type(2)));

#define NS 256              // samples (M)
#define KF 10000            // features (K)
#define KP 10048            // padded K (multiple of 64)
#define NO 15000            // outputs (N)
#define NP 15104            // padded N = 118*128
#define BM 256
#define BN 128
#define BK 32
#define KHALF (KP/2)        // 5024
#define NSTEPS (KHALF/BK)   // 157
#define COVR 150
#define NA 100

// ---------------- prep: BatchNorm affine + fp32 -> bf16 hi/lo split ----------------
__global__ void k_prep_x(const float* __restrict__ x, const float* __restrict__ gamma,
                         const float* __restrict__ beta, const float* __restrict__ rmean,
                         const float* __restrict__ rvar,
                         u16* __restrict__ xnh, u16* __restrict__ xnl)
{
    int k = blockIdx.x * 256 + threadIdx.x;
    int s = blockIdx.y;
    if (k >= KP) return;
    float v = 0.0f;
    if (k < KF) {
        float xv = x[(size_t)s * KF + k];
        v = (xv - rmean[k]) * (gamma[k] * rsqrtf(rvar[k] + 1e-5f)) + beta[k];
    }
    u32 bits = __float_as_uint(v);
    u32 hb   = bits & 0xffff0000u;
    float lo = v - __uint_as_float(hb);
    xnh[(size_t)s * KP + k] = (u16)(hb >> 16);
    xnl[(size_t)s * KP + k] = (u16)(__float_as_uint(lo) >> 16);
}

__device__ __forceinline__ void split_pack(float v0, float v1, u32& hp, u32& lp)
{
    u32 b0 = __float_as_uint(v0), b1 = __float_as_uint(v1);
    u32 h0 = b0 & 0xffff0000u,   h1 = b1 & 0xffff0000u;
    hp = (h0 >> 16) | h1;
    float r0 = v0 - __uint_as_float(h0);
    float r1 = v1 - __uint_as_float(h1);
    lp = (__float_as_uint(r0) >> 16) | (__float_as_uint(r1) & 0xffff0000u);
}

__device__ __forceinline__ void gload16(const u16* g, u16* l)
{
    __builtin_amdgcn_global_load_lds(
        (const __attribute__((address_space(1))) void*)g,
        (__attribute__((address_space(3))) void*)l, 16, 0, 0);
}

// ---------------- GEMM: Yp[ks] = Xn * W^T (3-term bf16 split), split-K=2 ----------------
// 1024 thr (16 waves, 4M x 4N, wave tile 64x32), BM=256 x BN=128, BK=32, dbuf LDS 96KB.
// ONE barrier/step, counted vmcnt(1); all frag reads issued together, compiler
// interleaves MFMA via fine-grained lgkmcnt. A via global_load_lds, W reg-staged early.
__global__ __launch_bounds__(1024, 4) void k_gemm(
    const u16* __restrict__ xnh, const u16* __restrict__ xnl,
    const float* __restrict__ W, float* __restrict__ Yp)
{
    __shared__ u16 Ah[2][BM * BK];
    __shared__ u16 Al[2][BM * BK];
    __shared__ u16 Bh[2][BN * BK];
    __shared__ u16 Bl[2][BN * BK];

    const int t    = threadIdx.x;
    const int wv   = t >> 6;
    const int n0   = blockIdx.x * BN;
    const int ks   = blockIdx.y;
    const int kbeg = ks * KHALF;

    // A staging: thread t -> LDS slot t (16B), global chunk pre-swizzled
    const int rA = t >> 2;
    const int uA = t & 3;
    const int cA = uA ^ ((rA >> 1) & 3);
    const size_t eA = (size_t)rA * KP + cA * 8;

    // W staging: thread t -> row rB, swizzled 8-elem chunk ch, half h2 (4 f32)
    const int rB  = t >> 3;
    const int ch  = (t >> 1) & 3;
    const int h2  = t & 1;
    const int gc  = ch ^ ((rB >> 1) & 3);
    const int kin = gc * 8 + h2 * 4;
    const int oW  = n0 + rB;
    const bool oOk = (oW < NO);
    const size_t eW = (size_t)(oOk ? oW : 0) * KF + kin;
    const int boff = rB * 32 + ch * 8 + h2 * 4;   // LDS elem offset (u16)

    // compute-side lane constants
    const int lane = t & 63;
    const int wm   = wv & 3;    // 4 M-groups of 64
    const int wn   = wv >> 2;   // 4 N-groups of 32
    const int l15  = lane & 15;
    const int lc   = lane >> 4;
    const int q    = (l15 >> 1) & 3;
    const int eoff = l15 * BK + ((lc ^ q) << 3);

    f32x4 acc[4][2];
#pragma unroll
    for (int m = 0; m < 4; ++m)
#pragma unroll
        for (int n = 0; n < 2; ++n) { acc[m][n][0]=0.f; acc[m][n][1]=0.f; acc[m][n][2]=0.f; acc[m][n][3]=0.f; }

    auto issueA = [&](int nb, int k1) {
        gload16(xnh + eA + k1, Ah[nb] + (wv << 9));
        gload16(xnl + eA + k1, Al[nb] + (wv << 9));
    };
    auto stageB = [&](int nb, f32x4 wv4, float msk) {
        wv4 *= msk;
        u32 h0, l0, h1, l1;
        split_pack(wv4[0], wv4[1], h0, l0);
        split_pack(wv4[2], wv4[3], h1, l1);
        u32x2 hv; hv[0] = h0; hv[1] = h1;
        u32x2 lv; lv[0] = l0; lv[1] = l1;
        *(u32x2*)(Bh[nb] + boff) = hv;
        *(u32x2*)(Bl[nb] + boff) = lv;
    };

    // prologue: A(0) DMA -> buf0; W(0) -> regs -> LDS buf0
    {
        issueA(0, kbeg);
        asm volatile("" ::: "memory");
        const bool okk = oOk && (kbeg + kin + 4 <= KF);
        const size_t wofs = okk ? (eW + kbeg) : 0;
        f32x4 w0 = *(const f32x4*)(W + wofs);
        stageB(0, w0, okk ? 1.f : 0.f);
    }

#pragma unroll 1
    for (int step = 0; step < NSTEPS; ++step) {
        const int p  = step & 1;
        const int nb = p ^ 1;
        const bool hasNext = (step + 1) < NSTEPS;
        const int k1 = kbeg + (step + 1) * BK;

        f32x4 nw; float nmsk = 0.f;
        if (hasNext) {
            const bool okk = oOk && (k1 + kin + 4 <= KF);
            const size_t wofs = okk ? (eW + k1) : 0;
            nw = *(const f32x4*)(W + wofs);
            nmsk = okk ? 1.f : 0.f;
        }

        // A(step) landed (W(step+1) may remain in flight); all LDS ops drained
        if (hasNext) { asm volatile("s_waitcnt vmcnt(1) lgkmcnt(0)" ::: "memory"); }
        else         { asm volatile("s_waitcnt vmcnt(0) lgkmcnt(0)" ::: "memory"); }
        __builtin_amdgcn_s_barrier();
        asm volatile("" ::: "memory");

        if (hasNext) { issueA(nb, k1); asm volatile("" ::: "memory"); }

        const u16* AhL = Ah[p]; const u16* AlL = Al[p];
        const u16* BhL = Bh[p]; const u16* BlL = Bl[p];

        bf16x8 fah[4], fal[4], fbh[2], fbl[2];
#pragma unroll
        for (int m = 0; m < 4; ++m) {
            const int off = (wm * 64 + m * 16) * BK + eoff;
            fah[m] = *(const bf16x8*)(AhL + off);
            fal[m] = *(const bf16x8*)(AlL + off);
        }
#pragma unroll
        for (int n = 0; n < 2; ++n) {
            const int off = (wn * 32 + n * 16) * BK + eoff;
            fbh[n] = *(const bf16x8*)(BhL + off);
            fbl[n] = *(const bf16x8*)(BlL + off);
        }

        __builtin_amdgcn_s_setprio(1);
#pragma unroll
        for (int m = 0; m < 4; ++m)
#pragma unroll
            for (int n = 0; n < 2; ++n) {
                acc[m][n] = __builtin_amdgcn_mfma_f32_16x16x32_bf16(fah[m], fbh[n], acc[m][n], 0, 0, 0);
                acc[m][n] = __builtin_amdgcn_mfma_f32_16x16x32_bf16(fah[m], fbl[n], acc[m][n], 0, 0, 0);
                acc[m][n] = __builtin_amdgcn_mfma_f32_16x16x32_bf16(fal[m], fbh[n], acc[m][n], 0, 0, 0);
            }
        __builtin_amdgcn_s_setprio(0);

        if (hasNext) stageB(nb, nw, nmsk);
    }

    // epilogue: C/D layout col = lane&15, row = (lane>>4)*4 + reg
    const int rowb = wm * 64 + lc * 4;
    const int colb = n0 + wn * 32 + l15;
#pragma unroll
    for (int m = 0; m < 4; ++m)
#pragma unroll
        for (int n = 0; n < 2; ++n) {
            const size_t base = ((size_t)(ks * NS + rowb + m * 16)) * NP + colb + n * 16;
            Yp[base]          = acc[m][n][0];
            Yp[base + NP]     = acc[m][n][1];
            Yp[base + 2*NP]   = acc[m][n][2];
            Yp[base + 3*NP]   = acc[m][n][3];
        }
}

// ---------------- per-sample: fused (reduce+bias+relu) -> cov -> chol -> w ----------------
// 512 thr. One r-pass builds Sum(yy^T) (two teams) AND column sums; A = (S - 150 mu mu^T)/149.
// Cholesky: reg tiles, 1 barrier/col, STATIC-INDEX publish (rule #20: no runtime reg-array
// indexing -> no scratch). Triangular solves: single wave, shuffle, 0 barriers.
__global__ __launch_bounds__(512, 1) void k_solve(const float* __restrict__ Yp,
                                                  const float* __restrict__ bias,
                                                  float* __restrict__ out)
{
    __shared__ float Ylds[15008];
    __shared__ float Lsh[13448];        // cov-partial buffer, then L (col-major, stride 105)
    __shared__ float mu[128];
    __shared__ float musum[2][112];
    __shared__ float dgi[112];
    __shared__ float usol[112];
    __shared__ float colbuf[2][112];
    __shared__ float redv[2];

    const int s = blockIdx.x;
    const int t = threadIdx.x;

    // fused split-K reduce + bias + relu into LDS
    const float* y0 = Yp + (size_t)s * NP;
    const float* y1 = Yp + (size_t)(NS + s) * NP;
    for (int o = t; o < 15000; o += 512)
        Ylds[o] = fmaxf(y0[o] + y1[o] + bias[o], 0.f);
    if (t < 8) Ylds[15000 + t] = 0.f;
    if (t >= 100 && t < 128) mu[t] = 0.f;
    if (t >= 104 && t < 112) { colbuf[0][t] = 0.f; colbuf[1][t] = 0.f; }
    __syncthreads();

    // two-team raw second-moment pass + column sums (by the ai==13 threads)
    const int team = t >> 8;
    const int tt   = t & 255;
    const int ai   = tt >> 4;
    const int bj   = tt & 15;
    const int r0   = ai * 8;
    const int c0   = bj * 7;
    const bool act = (ai < 13) && (bj < 15);
    const bool sumduty = (ai == 13);
    const int rbeg = team * 75;

    float A[8][7];
#pragma unroll
    for (int i = 0; i < 8; ++i)
#pragma unroll
        for (int j = 0; j < 7; ++j) A[i][j] = 0.f;
    float cs[7];
#pragma unroll
    for (int j = 0; j < 7; ++j) cs[j] = 0.f;

    for (int r = rbeg; r < rbeg + 75; ++r) {
        if (act) {
            float mi[8], mj[7];
#pragma unroll
            for (int i = 0; i < 8; ++i) mi[i] = Ylds[r * NA + r0 + i];
#pragma unroll
            for (int j = 0; j < 7; ++j) mj[j] = Ylds[r * NA + c0 + j];
#pragma unroll
            for (int i = 0; i < 8; ++i)
#pragma unroll
                for (int j = 0; j < 7; ++j) A[i][j] += mi[i] * mj[j];
        } else if (sumduty) {
#pragma unroll
            for (int j = 0; j < 7; ++j)
                if (c0 + j < NA) cs[j] += Ylds[r * NA + c0 + j];
        }
    }
    if (sumduty) {
#pragma unroll
        for (int j = 0; j < 7; ++j)
            if (c0 + j < NA) musum[team][c0 + j] = cs[j];
    }
    // team 1 publishes its partial tile
    if (team == 1 && act) {
#pragma unroll
        for (int i = 0; i < 8; ++i)
#pragma unroll
            for (int j = 0; j < 7; ++j)
                Lsh[(r0 + i) * 105 + (c0 + j)] = A[i][j];
    }
    __syncthreads();
    if (t < NA) mu[t] = (musum[0][t] + musum[1][t]) * (1.0f / COVR);
    __syncthreads();

    // team 0 merges: A = (S0 + S1 - 150 mu mu^T)/149
    if (team == 0 && act) {
        float mui[8], muj[7];
#pragma unroll
        for (int i = 0; i < 8; ++i) mui[i] = mu[r0 + i];
#pragma unroll
        for (int j = 0; j < 7; ++j) muj[j] = mu[c0 + j];
#pragma unroll
        for (int i = 0; i < 8; ++i)
#pragma unroll
            for (int j = 0; j < 7; ++j)
                A[i][j] = (A[i][j] + Lsh[(r0 + i) * 105 + (c0 + j)]
                           - (float)COVR * mui[i] * muj[j]) * (1.0f / 149.0f);
    }
    // seed column 0
    if (team == 0 && bj == 0 && ai < 13) {
#pragma unroll
        for (int i = 0; i < 8; ++i) colbuf[0][r0 + i] = A[i][0];
    }
    __syncthreads();

    // Cholesky: 1 barrier per column; L stored col-major Lsh[j*105+row]
    for (int j = 0; j < NA; ++j) {
        const int cb = j & 1;
        const float d = sqrtf(colbuf[cb][j]);
        const float dinv = 1.0f / d;
        if (t == 0) dgi[j] = dinv;

        if (team == 0 && act) {
            float Lr[8], Lc[7];
#pragma unroll
            for (int i = 0; i < 8; ++i) {
                const int row = r0 + i;
                const float cv = colbuf[cb][row];
                Lr[i] = (row > j) ? cv * dinv : (row == j ? d : 0.f);
            }
#pragma unroll
            for (int k = 0; k < 7; ++k) {
                const int col = c0 + k;
                const float cv = colbuf[cb][col];
                Lc[k] = (col > j) ? cv * dinv : (col == j ? d : 0.f);
            }
#pragma unroll
            for (int i = 0; i < 8; ++i)
#pragma unroll
                for (int k = 0; k < 7; ++k) A[i][k] -= Lr[i] * Lc[k];

            // owners of column j store L column (incl diag)
            if (bj == j / 7) {
#pragma unroll
                for (int i = 0; i < 8; ++i) Lsh[j * 105 + r0 + i] = Lr[i];
            }
            // owners of column j+1 publish its updated values — STATIC index only
            if (j + 1 < NA) {
                const int bjn = (j + 1) / 7;
                if (bj == bjn) {
                    const int jc = (j + 1) - bjn * 7;
#pragma unroll
                    for (int k = 0; k < 7; ++k) {
                        if (k == jc) {
#pragma unroll
                            for (int i = 0; i < 8; ++i) colbuf[cb ^ 1][r0 + i] = A[i][k];
                        }
                    }
                }
            }
        }
        __syncthreads();
    }

    // triangular solves: wave 0 only, shuffle broadcast, no barriers
    if (t < 64) {
        float r0c = 1.f, r1c = 1.f;
        float y0c = 0.f, y1c = 0.f;
        for (int j = 0; j < NA; ++j) {
            const float dj = dgi[j];
            float src = (j < 64) ? __shfl(r0c, j) : __shfl(r1c, j - 64);
            const float yj = src * dj;
            if (t == j) y0c = yj;
            if (t + 64 == j) y1c = yj;
            const float l0 = Lsh[j * 105 + t];
            const float l1 = Lsh[j * 105 + t + 64];
            if (t > j) r0c -= l0 * yj;
            if (t < 36 && t + 64 > j) r1c -= l1 * yj;
        }
        float u0c = 0.f, u1c = 0.f;
        for (int j = NA - 1; j >= 0; --j) {
            const float dj = dgi[j];
            float src = (j >= 64) ? __shfl(y1c, j - 64) : __shfl(y0c, j);
            const float uj = src * dj;
            if (t == j) u0c = uj;
            if (t + 64 == j) u1c = uj;
            const float l0 = Lsh[t * 105 + j];
            const float l1 = Lsh[(t + 64) * 105 + j];
            if (t < j) y0c -= l0 * uj;
            if (t < 36 && t + 64 < j) y1c -= l1 * uj;
        }
        usol[t] = u0c;
        if (t < 36) usol[t + 64] = u1c;
        float v = u0c + ((t < 36) ? u1c : 0.f);
        for (int off = 32; off > 0; off >>= 1) v += __shfl_xor(v, off);
        if (t == 0) redv[0] = 1.0f / v;
    }
    __syncthreads();
    if (t < NA) out[s * NA + t] = usol[t] * redv[0];
}

// ---------------- launcher ----------------
extern "C" void kernel_launch(void* const* d_in, const int* in_sizes, int n_in,
                              void* d_out, int out_size, void* d_ws, size_t ws_size,
                              hipStream_t stream)
{
    const float* x     = (const float*)d_in[0];
    const float* gamma = (const float*)d_in[1];
    const float* beta  = (const float*)d_in[2];
    const float* rm    = (const float*)d_in[3];
    const float* rv    = (const float*)d_in[4];
    const float* W     = (const float*)d_in[5];
    const float* b     = (const float*)d_in[6];
    float* out = (float*)d_out;

    char* ws = (char*)d_ws;
    u16*   xnh = (u16*)ws;                              // 5,144,576 B
    u16*   xnl = (u16*)(ws + 5144576);                  // 5,144,576 B
    float* Yp  = (float*)(ws + 10289152);               // 30,932,992 B
    (void)in_sizes; (void)n_in; (void)out_size; (void)ws_size;

    k_prep_x<<<dim3(40, NS), 256, 0, stream>>>(x, gamma, beta, rm, rv, xnh, xnl);
    k_gemm  <<<dim3(NP / BN, 2), 1024, 0, stream>>>(xnh, xnl, W, Yp);
    k_solve <<<dim3(NS), 512, 0, stream>>>(Yp, b, out);
}